// Round 8
// baseline (387.306 us; speedup 1.0000x reference)
//
#include <hip/hip_runtime.h>

// Discriminator GCN: x2 = sigmoid(GCN2(sigmoid(GCN1(x)))), N=4096, E=262144.
// Layer 1 as two bf16 MFMA GEMMs (dense S). GEMM2 fuses bias+sigmoid+W2-matvec.
// GEMM: 128x128 tile, BK=64, 4 waves/block, TWO blocks per CU (64KB LDS each).
// Co-resident blocks are not barrier-synced -> antiphase: one block's MFMAs
// overlap the other's ds_reads / staging drain (m114 mechanism). Per tile:
//   start: 8x global_load_lds (t+1 -> buf^1; full-tile lead ~= HBM latency)
//   reads kk0+kk1 (16x ds_read_b128, swizzled) ; 32 MFMA (compiler interleaves)
//   lgkmcnt(0); vmcnt(0); barrier   (drain hidden by the other block)

typedef __attribute__((ext_vector_type(8))) short bf16x8;
typedef __attribute__((ext_vector_type(4))) float f32x4;

#define NN 4096
#define NT 64   // K tiles of 64

__device__ __forceinline__ unsigned f2bf(float f) {
  unsigned u = __float_as_uint(f);
  return (u + 0x7FFFu + ((u >> 16) & 1u)) >> 16;   // RNE f32 -> bf16
}

#define GLDS(g, l) __builtin_amdgcn_global_load_lds(                      \
    (const __attribute__((address_space(1))) void*)(g),                   \
    (__attribute__((address_space(3))) void*)(l), 16, 0, 0)

// ---------------- small graph kernels ----------------

__global__ void init_deg_kernel(float* deg) {
  int v = blockIdx.x * 256 + threadIdx.x;
  if (v < NN) deg[v] = 1.0f;
}

__global__ void count_deg_kernel(const int* __restrict__ dst, int E, float* deg) {
  int e = blockIdx.x * 256 + threadIdx.x;
  if (e < E) atomicAdd(&deg[dst[e]], 1.0f);
}

__global__ void dinv_kernel(const float* __restrict__ deg, float* __restrict__ dinv) {
  int v = blockIdx.x * 256 + threadIdx.x;
  if (v < NN) dinv[v] = rsqrtf(deg[v]);
}

__global__ void diag_kernel(const float* __restrict__ dinv, float* __restrict__ S) {
  int v = blockIdx.x * 256 + threadIdx.x;
  if (v < NN) { float d = dinv[v]; S[(size_t)v * NN + v] = d * d; }
}

__global__ void scatter_S_kernel(const int* __restrict__ src, const int* __restrict__ dst,
                                 int E, const float* __restrict__ dinv, float* __restrict__ S) {
  int e = blockIdx.x * 256 + threadIdx.x;
  if (e < E) {
    int s = src[e], d = dst[e];
    atomicAdd(&S[(size_t)d * NN + s], dinv[s] * dinv[d]);
  }
}

// ---------------- casts ----------------

__global__ void cast_kernel(const float* __restrict__ in, unsigned short* __restrict__ out, int n) {
  int i = (blockIdx.x * 256 + threadIdx.x) * 8;
  if (i >= n) return;
  const float4* p = (const float4*)(in + i);
  float4 a = p[0], b = p[1];
  uint4 o;
  o.x = f2bf(a.x) | (f2bf(a.y) << 16);
  o.y = f2bf(a.z) | (f2bf(a.w) << 16);
  o.z = f2bf(b.x) | (f2bf(b.y) << 16);
  o.w = f2bf(b.z) | (f2bf(b.w) << 16);
  *(uint4*)(out + i) = o;
}

__global__ void transpose_cast_kernel(const float* __restrict__ W, unsigned short* __restrict__ WT) {
  __shared__ float tile[32][33];
  int bx = blockIdx.x * 32, by = blockIdx.y * 32;
  int tx = threadIdx.x, ty = threadIdx.y;
#pragma unroll
  for (int i = 0; i < 32; i += 8)
    tile[ty + i][tx] = W[(size_t)(by + ty + i) * NN + bx + tx];
  __syncthreads();
#pragma unroll
  for (int i = 0; i < 32; i += 8)
    WT[(size_t)(bx + ty + i) * NN + by + tx] = (unsigned short)f2bf(tile[tx][ty + i]);
}

// ------------- 128x128 bf16 GEMM: C[M][N] = A[M][K] * BT[N][K]^T -------------
// LDS per buf (32KB): A [128][64] bf16 rows 128B with 16B-granule XOR swizzle;
// B same at +16KB. Pieces = 32 rows (4KB); one GLDS line covers all 4 waves
// (wave-uniform dest piece*4096 + wid*1024). Double buffer at bit 15.

template <int EPI>  // 0: bf16 C store; 1: fused sigmoid(acc+b1)*W2 -> atomic h2
__global__ __launch_bounds__(256, 2) void gemm128_kernel(
    const unsigned short* __restrict__ A, const unsigned short* __restrict__ BT,
    unsigned short* __restrict__ C, const float* __restrict__ bias,
    const float* __restrict__ W2, float* __restrict__ h2) {
  __shared__ __align__(16) char smem[65536];
  const int tid = threadIdx.x;
  const int lane = tid & 63, wid = tid >> 6;
  const int wr = wid >> 1, wc = wid & 1;     // 2x2 wave grid; wave owns 64x64 of C

  // grid 1024 = 32x32 panels; bijective 2D XCD chunk: XCD owns 8 rowPanels x 16 colPanels
  const int bid = blockIdx.x;
  const int xcd = bid & 7, loc = bid >> 3;
  const int rowBase = (((xcd >> 1) << 3) + (loc >> 4)) << 7;
  const int colBase = (((xcd & 1) << 4) + (loc & 15)) << 7;

  // staging source (pre-swizzled column so linear LDS dest = swizzled layout)
  const int srow = tid >> 3;                              // 0..31 within a piece
  const int scolb = ((tid & 7) << 4) ^ ((srow & 7) << 4);
  const unsigned short* pA = A + (size_t)(rowBase + srow) * NN + (scolb >> 1);
  const unsigned short* pB = BT + (size_t)(colBase + srow) * NN + (scolb >> 1);

  // ds_read swizzled column constants
  const int rl = lane & 15;
  const int c0 = ((lane >> 4) << 4) ^ ((lane & 7) << 4);  // kk=0 physical col byte
  const int c1 = c0 ^ 64;                                  // kk=1
  const int aoff = (wr * 64 + rl) * 128;           // A row byte base
  const int boff = 16384 + (wc * 64 + rl) * 128;   // B row byte base

  f32x4 acc[4][4] = {};
  bf16x8 a0[4], a1[4], b0[4], b1[4];

  // prologue: stage tile0 -> buf0
  {
    char* w0 = smem + (wid << 10);
    GLDS(pA + (size_t)0 * 32 * NN, w0 + 0 * 4096);
    GLDS(pA + (size_t)1 * 32 * NN, w0 + 1 * 4096);
    GLDS(pA + (size_t)2 * 32 * NN, w0 + 2 * 4096);
    GLDS(pA + (size_t)3 * 32 * NN, w0 + 3 * 4096);
    GLDS(pB + (size_t)0 * 32 * NN, w0 + 16384 + 0 * 4096);
    GLDS(pB + (size_t)1 * 32 * NN, w0 + 16384 + 1 * 4096);
    GLDS(pB + (size_t)2 * 32 * NN, w0 + 16384 + 2 * 4096);
    GLDS(pB + (size_t)3 * 32 * NN, w0 + 16384 + 3 * 4096);
    asm volatile("s_waitcnt vmcnt(0)" ::: "memory");
    __builtin_amdgcn_s_barrier();
  }

#pragma unroll 2
  for (int t = 0; t < NT; ++t) {
    const char* lb = smem + ((t & 1) << 15);
    char* st = smem + (((t & 1) ^ 1) << 15) + (wid << 10);
    // t=NT-1 stages one tile past the operand end: lands in adjacent workspace
    // regions (audited in kernel_launch), never consumed.
    const unsigned short* s1A = pA + (size_t)(t + 1) * 64;
    const unsigned short* s1B = pB + (size_t)(t + 1) * 64;

    // ---- stage ALL of t+1 into buf^1 (dead since previous tile-end fence) ----
    GLDS(s1A + (size_t)0 * 32 * NN, st + 0 * 4096);
    GLDS(s1A + (size_t)1 * 32 * NN, st + 1 * 4096);
    GLDS(s1A + (size_t)2 * 32 * NN, st + 2 * 4096);
    GLDS(s1A + (size_t)3 * 32 * NN, st + 3 * 4096);
    GLDS(s1B + (size_t)0 * 32 * NN, st + 16384 + 0 * 4096);
    GLDS(s1B + (size_t)1 * 32 * NN, st + 16384 + 1 * 4096);
    GLDS(s1B + (size_t)2 * 32 * NN, st + 16384 + 2 * 4096);
    GLDS(s1B + (size_t)3 * 32 * NN, st + 16384 + 3 * 4096);

    // ---- fragment reads (compiler emits counted lgkmcnt; free to interleave) ----
#pragma unroll
    for (int m = 0; m < 4; ++m) a0[m] = *(const bf16x8*)(lb + aoff + m * 2048 + c0);
#pragma unroll
    for (int n = 0; n < 4; ++n) b0[n] = *(const bf16x8*)(lb + boff + n * 2048 + c0);
#pragma unroll
    for (int m = 0; m < 4; ++m) a1[m] = *(const bf16x8*)(lb + aoff + m * 2048 + c1);
#pragma unroll
    for (int n = 0; n < 4; ++n) b1[n] = *(const bf16x8*)(lb + boff + n * 2048 + c1);

    // ---- 32 MFMA ----
    __builtin_amdgcn_s_setprio(1);
#pragma unroll
    for (int m = 0; m < 4; ++m)
#pragma unroll
      for (int n = 0; n < 4; ++n)
        acc[m][n] = __builtin_amdgcn_mfma_f32_16x16x32_bf16(a0[m], b0[n], acc[m][n], 0, 0, 0);
#pragma unroll
    for (int m = 0; m < 4; ++m)
#pragma unroll
      for (int n = 0; n < 4; ++n)
        acc[m][n] = __builtin_amdgcn_mfma_f32_16x16x32_bf16(a1[m], b1[n], acc[m][n], 0, 0, 0);
    __builtin_amdgcn_s_setprio(0);

    // ---- tile fence: my reads retired; t+1 landed; buf handoff ----
    asm volatile("s_waitcnt lgkmcnt(0)" ::: "memory");
    asm volatile("s_waitcnt vmcnt(0)" ::: "memory");
    __builtin_amdgcn_s_barrier();
  }

  // ---- epilogue ----
  const int orow = rowBase + wr * 64 + (lane >> 4) * 4;
  const int ocol = colBase + wc * 64 + rl;
  if (EPI == 0) {
#pragma unroll
    for (int n = 0; n < 4; ++n) {
      int ccol = ocol + n * 16;
#pragma unroll
      for (int m = 0; m < 4; ++m) {
#pragma unroll
        for (int i = 0; i < 4; ++i) {
          C[(size_t)(orow + m * 16 + i) * NN + ccol] = (unsigned short)f2bf(acc[m][n][i]);
        }
      }
    }
  } else {
    // x1 = sigmoid(acc + b1[col]); h2[row] += sum_col x1*W2[col]
    float bv[4], wv[4];
#pragma unroll
    for (int n = 0; n < 4; ++n) { bv[n] = bias[ocol + n * 16]; wv[n] = W2[ocol + n * 16]; }
#pragma unroll
    for (int m = 0; m < 4; ++m) {
#pragma unroll
      for (int i = 0; i < 4; ++i) {
        float s = 0.0f;
#pragma unroll
        for (int n = 0; n < 4; ++n) {
          float x = 1.0f / (1.0f + __expf(-(acc[m][n][i] + bv[n])));
          s += x * wv[n];
        }
        s += __shfl_xor(s, 1);
        s += __shfl_xor(s, 2);
        s += __shfl_xor(s, 4);
        s += __shfl_xor(s, 8);
        if ((lane & 15) == 0) atomicAdd(&h2[orow + m * 16 + i], s);
      }
    }
  }
}

// ---------------- layer 2 tail ----------------

__global__ void init_t_kernel(const float* __restrict__ dinv, const float* __restrict__ h2,
                              const float* __restrict__ b2, float* __restrict__ tacc) {
  int v = blockIdx.x * 256 + threadIdx.x;
  if (v < NN) tacc[v] = dinv[v] * dinv[v] * h2[v] + b2[0];
}

__global__ void scatter_t_kernel(const int* __restrict__ src, const int* __restrict__ dst,
                                 int E, const float* __restrict__ dinv,
                                 const float* __restrict__ h2, float* __restrict__ tacc) {
  int e = blockIdx.x * 256 + threadIdx.x;
  if (e < E) {
    int s = src[e], d = dst[e];
    atomicAdd(&tacc[d], dinv[s] * dinv[d] * h2[s]);
  }
}

__global__ void final_kernel(const float* __restrict__ tacc, float* __restrict__ out) {
  int v = blockIdx.x * 256 + threadIdx.x;
  if (v < NN) out[v] = 1.0f / (1.0f + __expf(-tacc[v]));
}

// ---------------- launch ----------------

extern "C" void kernel_launch(void* const* d_in, const int* in_sizes, int n_in,
                              void* d_out, int out_size, void* d_ws, size_t ws_size,
                              hipStream_t stream) {
  const float* x  = (const float*)d_in[0];
  const int*   ei = (const int*)d_in[1];
  const float* W1 = (const float*)d_in[2];
  const float* b1 = (const float*)d_in[3];
  const float* W2 = (const float*)d_in[4];
  const float* b2 = (const float*)d_in[5];
  float* out = (float*)d_out;
  const int E = in_sizes[1] / 2;
  const int* esrc = ei;
  const int* edst = ei + E;

  char* w = (char*)d_ws;
  float*          Sf  = (float*)w;                                  // [0,64M) f32 dense S
  unsigned short* H1T = (unsigned short*)w;                         // [0,32M)  (after Sf dead)
  unsigned short* W1T = (unsigned short*)(w + (size_t)(32u << 20)); // [32M,64M)
  unsigned short* Sbf = (unsigned short*)(w + (size_t)(64u << 20)); // [64M,96M)
  unsigned short* Xbf = (unsigned short*)(w + (size_t)(96u << 20)); // [96M,128M)
  float* deg  = (float*)(w + (size_t)(128u << 20));
  float* dinv = deg + 4096;
  float* h2   = deg + 8192;
  float* tacc = deg + 12288;

  // graph normalization
  init_deg_kernel<<<16, 256, 0, stream>>>(deg);
  count_deg_kernel<<<(E + 255) / 256, 256, 0, stream>>>(edst, E, deg);
  dinv_kernel<<<16, 256, 0, stream>>>(deg, dinv);

  // dense S (f32, atomics sum duplicate edges), then cast to bf16
  hipMemsetAsync(Sf, 0, (size_t)64 << 20, stream);
  hipMemsetAsync(h2, 0, 4096 * sizeof(float), stream);
  diag_kernel<<<16, 256, 0, stream>>>(dinv, Sf);
  scatter_S_kernel<<<(E + 255) / 256, 256, 0, stream>>>(esrc, edst, E, dinv, Sf);
  cast_kernel<<<8192, 256, 0, stream>>>(Sf, Sbf, NN * NN);

  // operand preparation
  cast_kernel<<<8192, 256, 0, stream>>>(x, Xbf, NN * NN);
  transpose_cast_kernel<<<dim3(128, 128), dim3(32, 8), 0, stream>>>(W1, W1T);

  // layer 1: GEMM1 (H1T), then GEMM2 with fused sigmoid + W2 matvec -> h2
  gemm128_kernel<0><<<1024, 256, 0, stream>>>(W1T, Xbf, H1T, nullptr, nullptr, nullptr);
  gemm128_kernel<1><<<1024, 256, 0, stream>>>(Sbf, H1T, nullptr, b1, W2, h2);

  // layer 2 tail: scalar aggregation + sigmoid
  init_t_kernel<<<16, 256, 0, stream>>>(dinv, h2, b2, tacc);
  scatter_t_kernel<<<(E + 255) / 256, 256, 0, stream>>>(esrc, edst, E, dinv, h2, tacc);
  final_kernel<<<16, 256, 0, stream>>>(tacc, out);
}

// Round 9
// 324.827 us; speedup vs baseline: 1.1923x; 1.1923x over previous
//
#include <hip/hip_runtime.h>

// Discriminator GCN: x2 = sigmoid(GCN2(sigmoid(GCN1(x)))), N=4096, E=262144.
// Layer 1 as two bf16 MFMA GEMMs (dense S built DIRECTLY in bf16 via CAS-add).
// GEMM2 fuses bias+sigmoid+W2-matvec. GEMM = r5 structure (best of 5 variants):
// 256x256 tile, BK=64, 8 waves, register software pipeline, barrier at P3-end,
// P4 preloads next tile's frags under its MFMAs.

typedef __attribute__((ext_vector_type(8))) short bf16x8;
typedef __attribute__((ext_vector_type(4))) float f32x4;

#define NN 4096
#define NT 64   // K tiles of 64

__device__ __forceinline__ unsigned f2bf(float f) {
  unsigned u = __float_as_uint(f);
  return (u + 0x7FFFu + ((u >> 16) & 1u)) >> 16;   // RNE f32 -> bf16
}

#define GLDS(g, l) __builtin_amdgcn_global_load_lds(                      \
    (const __attribute__((address_space(1))) void*)(g),                   \
    (__attribute__((address_space(3))) void*)(l), 16, 0, 0)

// ---------------- small graph kernels ----------------

__global__ void init_deg_kernel(float* deg) {
  int v = blockIdx.x * 256 + threadIdx.x;
  if (v < NN) deg[v] = 1.0f;
}

__global__ void count_deg_kernel(const int* __restrict__ dst, int E, float* deg) {
  int e = blockIdx.x * 256 + threadIdx.x;
  if (e < E) atomicAdd(&deg[dst[e]], 1.0f);
}

__global__ void dinv_kernel(const float* __restrict__ deg, float* __restrict__ dinv) {
  int v = blockIdx.x * 256 + threadIdx.x;
  if (v < NN) dinv[v] = rsqrtf(deg[v]);
}

// diagonal first (plain store), THEN edge scatter CAS-adds on top (self-edges sum).
__global__ void diag_bf16_kernel(const float* __restrict__ dinv, unsigned short* __restrict__ Sbf) {
  int v = blockIdx.x * 256 + threadIdx.x;
  if (v < NN) { float d = dinv[v]; Sbf[(size_t)v * NN + v] = (unsigned short)f2bf(d * d); }
}

__global__ void scatter_bf16_kernel(const int* __restrict__ src, const int* __restrict__ dst,
                                    int E, const float* __restrict__ dinv,
                                    unsigned int* __restrict__ Sw) {
  int e = blockIdx.x * 256 + threadIdx.x;
  if (e >= E) return;
  int s = src[e], d = dst[e];
  float val = dinv[s] * dinv[d];
  size_t idx = (size_t)d * NN + s;
  unsigned int* p = Sw + (idx >> 1);
  const bool hi = (idx & 1) != 0;
  unsigned old = *p, assumed;
  do {
    assumed = old;
    unsigned short cur = hi ? (unsigned short)(assumed >> 16) : (unsigned short)(assumed & 0xFFFFu);
    float f = __uint_as_float(((unsigned)cur) << 16) + val;
    unsigned short nb = (unsigned short)f2bf(f);
    unsigned nw = hi ? ((assumed & 0x0000FFFFu) | ((unsigned)nb << 16))
                     : ((assumed & 0xFFFF0000u) | (unsigned)nb);
    old = atomicCAS(p, assumed, nw);
  } while (old != assumed);
}

// ---------------- casts ----------------

__global__ void cast_kernel(const float* __restrict__ in, unsigned short* __restrict__ out, int n) {
  int i = (blockIdx.x * 256 + threadIdx.x) * 8;
  if (i >= n) return;
  const float4* p = (const float4*)(in + i);
  float4 a = p[0], b = p[1];
  uint4 o;
  o.x = f2bf(a.x) | (f2bf(a.y) << 16);
  o.y = f2bf(a.z) | (f2bf(a.w) << 16);
  o.z = f2bf(b.x) | (f2bf(b.y) << 16);
  o.w = f2bf(b.z) | (f2bf(b.w) << 16);
  *(uint4*)(out + i) = o;
}

// 64x64 f32 tile; coalesced 256B reads, ushort4 (8B/lane) bf16 transposed stores.
__global__ void transpose_cast_kernel(const float* __restrict__ W, unsigned short* __restrict__ WT) {
  __shared__ float tile[64][65];
  const int tid = threadIdx.x;
  const int bx = blockIdx.x * 64, by = blockIdx.y * 64;
  const int tx = tid & 63, ty = tid >> 6;      // 64 x 4
#pragma unroll
  for (int i = 0; i < 64; i += 4)
    tile[ty + i][tx] = W[(size_t)(by + ty + i) * NN + bx + tx];
  __syncthreads();
  const int wtx = tid & 15, wty = tid >> 4;    // 16 x 16
#pragma unroll
  for (int i = 0; i < 64; i += 16) {
    int r = wty + i;                            // output row offset = orig col
    ushort4 v;
    v.x = (unsigned short)f2bf(tile[4 * wtx + 0][r]);
    v.y = (unsigned short)f2bf(tile[4 * wtx + 1][r]);
    v.z = (unsigned short)f2bf(tile[4 * wtx + 2][r]);
    v.w = (unsigned short)f2bf(tile[4 * wtx + 3][r]);
    *(ushort4*)(WT + (size_t)(bx + r) * NN + by + 4 * wtx) = v;
  }
}

// ------------- 256x256 bf16 GEMM: C[M][N] = A[M][K] * BT[N][K]^T -------------
// (r5 structure, verbatim.) LDS per buf (64KB): A [256][64] bf16 rows 128B with
// 16B-granule XOR swizzle; B at +32KB. Pieces (64 rows = 8KB): A0..A3, B0..B3.
// Staging of t+1: P1: B0,B1,B2  P2: B3,A0,A2  P3: A1,A3.
// Guards: P1-end vmcnt(3); P3-end lgkmcnt(0)+vmcnt(2)+barrier. P4 preloads next
// tile's P1 frags before its MFMAs.

template <int EPI>  // 0: bf16 C store; 1: fused sigmoid(acc+b1)*W2 -> atomic h2
__global__ __launch_bounds__(512, 2) void gemm256_kernel(
    const unsigned short* __restrict__ A, const unsigned short* __restrict__ BT,
    unsigned short* __restrict__ C, const float* __restrict__ bias,
    const float* __restrict__ W2, float* __restrict__ h2) {
  __shared__ __align__(16) char smem[131072];
  const int tid = threadIdx.x;
  const int lane = tid & 63, wid = tid >> 6;
  const int wr = wid >> 2, wc = wid & 3;     // 2x4 wave grid; wave owns 128x64 of C

  const int bid = blockIdx.x;
  const int swz = (bid & 7) * 32 + (bid >> 3);   // XCD-aware remap (256 = 8*32)
  const int rowBase = (swz >> 4) * 256;
  const int colBase = (swz & 15) * 256;

  const int srow = tid >> 3;                              // 0..63 within a piece
  const int scolb = ((tid & 7) << 4) ^ ((srow & 7) << 4);
  const unsigned short* pA = A + (size_t)(rowBase + srow) * NN + (scolb >> 1);
  const unsigned short* pB = BT + (size_t)(colBase + srow) * NN + (scolb >> 1);

  const int rl = lane & 15;
  const int c0 = ((lane >> 4) << 4) ^ ((lane & 7) << 4);  // kk=0 physical col byte
  const int c1 = c0 ^ 64;                                  // kk=1
  const int aoff = (wr * 128 + rl) * 128;          // A row byte base (mh0,m=0)
  const int boff = 32768 + (wc * 64 + rl) * 128;   // B row byte base

  f32x4 acc[8][4] = {};
  bf16x8 bk0[4], bk1[4], afA[4], afB[4];

  // prologue: stage tile0 -> buf0 (A-odd last), preload P1 frags
  {
    char* w0 = smem + (wid << 10);
    GLDS(pB + (size_t)0 * 64 * NN, w0 + 32768 + 0 * 8192);
    GLDS(pB + (size_t)1 * 64 * NN, w0 + 32768 + 1 * 8192);
    GLDS(pB + (size_t)2 * 64 * NN, w0 + 32768 + 2 * 8192);
    GLDS(pB + (size_t)3 * 64 * NN, w0 + 32768 + 3 * 8192);
    GLDS(pA + (size_t)0 * 64 * NN, w0 + 0 * 8192);
    GLDS(pA + (size_t)2 * 64 * NN, w0 + 2 * 8192);
    GLDS(pA + (size_t)1 * 64 * NN, w0 + 1 * 8192);
    GLDS(pA + (size_t)3 * 64 * NN, w0 + 3 * 8192);
    asm volatile("s_waitcnt vmcnt(2)" ::: "memory");
    __builtin_amdgcn_s_barrier();
#pragma unroll
    for (int m = 0; m < 4; ++m) afA[m] = *(const bf16x8*)(smem + aoff + m * 2048 + c0);
#pragma unroll
    for (int n = 0; n < 4; ++n) bk0[n] = *(const bf16x8*)(smem + boff + n * 2048 + c0);
  }

#pragma unroll 2
  for (int t = 0; t < NT; ++t) {
    const char* lb = smem + ((t & 1) << 16);
    char* st = smem + (((t & 1) ^ 1) << 16) + (wid << 10);
    // t=NT-1 stages one tile past the operand end: lands in adjacent workspace
    // regions (audited in kernel_launch), never consumed.
    const unsigned short* s1A = pA + (size_t)(t + 1) * 64;
    const unsigned short* s1B = pB + (size_t)(t + 1) * 64;

    // ---- P1: MFMA(mh0,k0) on afA,bk0; prefetch P2 frags; stage B012(t+1) ----
    GLDS(s1B + (size_t)0 * 64 * NN, st + 32768 + 0 * 8192);
    GLDS(s1B + (size_t)1 * 64 * NN, st + 32768 + 1 * 8192);
    GLDS(s1B + (size_t)2 * 64 * NN, st + 32768 + 2 * 8192);
#pragma unroll
    for (int m = 0; m < 4; ++m) afB[m] = *(const bf16x8*)(lb + aoff + m * 2048 + c1);
#pragma unroll
    for (int n = 0; n < 4; ++n) bk1[n] = *(const bf16x8*)(lb + boff + n * 2048 + c1);
    __builtin_amdgcn_s_setprio(1);
#pragma unroll
    for (int m = 0; m < 4; ++m)
#pragma unroll
      for (int n = 0; n < 4; ++n)
        acc[m][n] = __builtin_amdgcn_mfma_f32_16x16x32_bf16(afA[m], bk0[n], acc[m][n], 0, 0, 0);
    __builtin_amdgcn_s_setprio(0);
    asm volatile("s_waitcnt vmcnt(3)" ::: "memory");   // A-odd(t) landed
    __builtin_amdgcn_sched_barrier(0);

    // ---- P2: MFMA(mh0,k1) on afB,bk1; prefetch P3 frags; stage B3,A0,A2(t+1) ----
    GLDS(s1B + (size_t)3 * 64 * NN, st + 32768 + 3 * 8192);
    GLDS(s1A + (size_t)0 * 64 * NN, st + 0 * 8192);
    GLDS(s1A + (size_t)2 * 64 * NN, st + 2 * 8192);
#pragma unroll
    for (int m = 0; m < 4; ++m) afA[m] = *(const bf16x8*)(lb + aoff + (4 + m) * 2048 + c0);
    __builtin_amdgcn_s_setprio(1);
#pragma unroll
    for (int m = 0; m < 4; ++m)
#pragma unroll
      for (int n = 0; n < 4; ++n)
        acc[m][n] = __builtin_amdgcn_mfma_f32_16x16x32_bf16(afB[m], bk1[n], acc[m][n], 0, 0, 0);
    __builtin_amdgcn_s_setprio(0);
    __builtin_amdgcn_sched_barrier(0);

    // ---- P3: MFMA(mh1,k0) on afA,bk0; prefetch P4 frags; stage A1,A3(t+1);
    //         tile-end sync HERE (no lb reads after this phase) ----
    GLDS(s1A + (size_t)1 * 64 * NN, st + 1 * 8192);
    GLDS(s1A + (size_t)3 * 64 * NN, st + 3 * 8192);
#pragma unroll
    for (int m = 0; m < 4; ++m) afB[m] = *(const bf16x8*)(lb + aoff + (4 + m) * 2048 + c1);
    __builtin_amdgcn_s_setprio(1);
#pragma unroll
    for (int m = 0; m < 4; ++m)
#pragma unroll
      for (int n = 0; n < 4; ++n)
        acc[4 + m][n] = __builtin_amdgcn_mfma_f32_16x16x32_bf16(afA[m], bk0[n], acc[4 + m][n], 0, 0, 0);
    __builtin_amdgcn_s_setprio(0);
    asm volatile("s_waitcnt lgkmcnt(0)" ::: "memory");  // wave's lb reads retired
    asm volatile("s_waitcnt vmcnt(2)" ::: "memory");    // 6 early pieces of t+1 landed
    __builtin_amdgcn_s_barrier();                       // buf reuse fence (1 per tile)
    __builtin_amdgcn_sched_barrier(0);

    // ---- P4: preload next tile's P1 frags (lands under MFMAs); MFMA(mh1,k1) ----
    {
      const char* nb = smem + (((t + 1) & 1) << 16);
#pragma unroll
      for (int m = 0; m < 4; ++m) afA[m] = *(const bf16x8*)(nb + aoff + m * 2048 + c0);
#pragma unroll
      for (int n = 0; n < 4; ++n) bk0[n] = *(const bf16x8*)(nb + boff + n * 2048 + c0);
    }
    __builtin_amdgcn_s_setprio(1);
#pragma unroll
    for (int m = 0; m < 4; ++m)
#pragma unroll
      for (int n = 0; n < 4; ++n)
        acc[4 + m][n] = __builtin_amdgcn_mfma_f32_16x16x32_bf16(afB[m], bk1[n], acc[4 + m][n], 0, 0, 0);
    __builtin_amdgcn_s_setprio(0);
    __builtin_amdgcn_sched_barrier(0);
  }

  // ---- epilogue ----
  const int orow = rowBase + wr * 128 + (lane >> 4) * 4;
  const int ocol = colBase + wc * 64 + (lane & 15);
  if (EPI == 0) {
#pragma unroll
    for (int n = 0; n < 4; ++n) {
      int ccol = ocol + n * 16;
#pragma unroll
      for (int m = 0; m < 8; ++m) {
#pragma unroll
        for (int i = 0; i < 4; ++i) {
          C[(size_t)(orow + m * 16 + i) * NN + ccol] = (unsigned short)f2bf(acc[m][n][i]);
        }
      }
    }
  } else {
    // x1 = sigmoid(acc + b1[col]); h2[row] += sum_col x1*W2[col]
    float bv[4], wv[4];
#pragma unroll
    for (int n = 0; n < 4; ++n) { bv[n] = bias[ocol + n * 16]; wv[n] = W2[ocol + n * 16]; }
#pragma unroll
    for (int m = 0; m < 8; ++m) {
#pragma unroll
      for (int i = 0; i < 4; ++i) {
        float s = 0.0f;
#pragma unroll
        for (int n = 0; n < 4; ++n) {
          float x = 1.0f / (1.0f + __expf(-(acc[m][n][i] + bv[n])));
          s += x * wv[n];
        }
        s += __shfl_xor(s, 1);
        s += __shfl_xor(s, 2);
        s += __shfl_xor(s, 4);
        s += __shfl_xor(s, 8);
        if ((lane & 15) == 0) atomicAdd(&h2[orow + m * 16 + i], s);
      }
    }
  }
}

// ---------------- layer 2 tail ----------------

__global__ void init_t_kernel(const float* __restrict__ dinv, const float* __restrict__ h2,
                              const float* __restrict__ b2, float* __restrict__ tacc) {
  int v = blockIdx.x * 256 + threadIdx.x;
  if (v < NN) tacc[v] = dinv[v] * dinv[v] * h2[v] + b2[0];
}

__global__ void scatter_t_kernel(const int* __restrict__ src, const int* __restrict__ dst,
                                 int E, const float* __restrict__ dinv,
                                 const float* __restrict__ h2, float* __restrict__ tacc) {
  int e = blockIdx.x * 256 + threadIdx.x;
  if (e < E) {
    int s = src[e], d = dst[e];
    atomicAdd(&tacc[d], dinv[s] * dinv[d] * h2[s]);
  }
}

__global__ void final_kernel(const float* __restrict__ tacc, float* __restrict__ out) {
  int v = blockIdx.x * 256 + threadIdx.x;
  if (v < NN) out[v] = 1.0f / (1.0f + __expf(-tacc[v]));
}

// ---------------- launch ----------------

extern "C" void kernel_launch(void* const* d_in, const int* in_sizes, int n_in,
                              void* d_out, int out_size, void* d_ws, size_t ws_size,
                              hipStream_t stream) {
  const float* x  = (const float*)d_in[0];
  const int*   ei = (const int*)d_in[1];
  const float* W1 = (const float*)d_in[2];
  const float* b1 = (const float*)d_in[3];
  const float* W2 = (const float*)d_in[4];
  const float* b2 = (const float*)d_in[5];
  float* out = (float*)d_out;
  const int E = in_sizes[1] / 2;
  const int* esrc = ei;
  const int* edst = ei + E;

  char* w = (char*)d_ws;
  unsigned short* H1T = (unsigned short*)w;                         // [0,32M)
  unsigned short* W1T = (unsigned short*)(w + (size_t)(32u << 20)); // [32M,64M)
  unsigned short* Sbf = (unsigned short*)(w + (size_t)(64u << 20)); // [64M,96M) built in bf16
  unsigned short* Xbf = (unsigned short*)(w + (size_t)(96u << 20)); // [96M,128M)
  float* deg  = (float*)(w + (size_t)(128u << 20));
  float* dinv = deg + 4096;
  float* h2   = deg + 8192;
  float* tacc = deg + 12288;

  // graph normalization
  init_deg_kernel<<<16, 256, 0, stream>>>(deg);
  count_deg_kernel<<<(E + 255) / 256, 256, 0, stream>>>(edst, E, deg);
  dinv_kernel<<<16, 256, 0, stream>>>(deg, dinv);

  // dense S directly in bf16: memset 32MB, diag plain store, edges CAS-add
  hipMemsetAsync(Sbf, 0, (size_t)32 << 20, stream);
  hipMemsetAsync(h2, 0, 4096 * sizeof(float), stream);
  diag_bf16_kernel<<<16, 256, 0, stream>>>(dinv, Sbf);
  scatter_bf16_kernel<<<(E + 255) / 256, 256, 0, stream>>>(esrc, edst, E, dinv,
                                                           (unsigned int*)Sbf);

  // operand preparation
  cast_kernel<<<8192, 256, 0, stream>>>(x, Xbf, NN * NN);
  transpose_cast_kernel<<<dim3(64, 64), 256, 0, stream>>>(W1, W1T);

  // layer 1: GEMM1 (H1T), then GEMM2 with fused sigmoid + W2 matvec -> h2
  gemm256_kernel<0><<<256, 512, 0, stream>>>(W1T, Xbf, H1T, nullptr, nullptr, nullptr);
  gemm256_kernel<1><<<256, 512, 0, stream>>>(Sbf, H1T, nullptr, b1, W2, h2);

  // layer 2 tail: scalar aggregation + sigmoid
  init_t_kernel<<<16, 256, 0, stream>>>(dinv, h2, b2, tacc);
  scatter_t_kernel<<<(E + 255) / 256, 256, 0, stream>>>(esrc, edst, E, dinv, h2, tacc);
  final_kernel<<<16, 256, 0, stream>>>(tacc, out);
}